// Round 5
// baseline (363.177 us; speedup 1.0000x reference)
//
#include <hip/hip_runtime.h>

typedef unsigned short u16;
typedef __attribute__((ext_vector_type(8))) short bf16x8;
typedef __attribute__((ext_vector_type(4))) float f32x4;

#define MFMA16x16x32 __builtin_amdgcn_mfma_f32_16x16x32_bf16

static __device__ __forceinline__ float bf2f(u16 h) {
    unsigned int u = ((unsigned int)h) << 16;
    return __builtin_bit_cast(float, u);
}
static __device__ __forceinline__ u16 f2bf(float f) {
    unsigned int u = __builtin_bit_cast(unsigned int, f);
    u = (u + 0x7FFFu + ((u >> 16) & 1u)) >> 16;   // RNE
    return (u16)u;
}
// split fp32 into hi = truncate-to-bf16, lo = bf16(v - hi);  v ~= hi + lo
static __device__ __forceinline__ void fsplit(float v, u16& hi, u16& lo) {
    unsigned int u = __builtin_bit_cast(unsigned int, v);
    hi = (u16)(u >> 16);
    const float fh = __builtin_bit_cast(float, u & 0xFFFF0000u);
    lo = f2bf(v - fh);
}
static __device__ __forceinline__ void f4_split(const float4 v, u16* hi, u16* lo) {
    fsplit(v.x, hi[0], lo[0]); fsplit(v.y, hi[1], lo[1]);
    fsplit(v.z, hi[2], lo[2]); fsplit(v.w, hi[3], lo[3]);
}

// ---------------------------------------------------------------------------
// Kernel 1: Q/K/V projection with split-bf16 (3-term MFMA ~ fp32 accuracy).
// Y = X @ W^T + b.  z in {Q,K,V}; Q,K written fp32 (feed split QK^T),
// V written bf16 (feeds PV, low sensitivity).
// ---------------------------------------------------------------------------
__global__ __launch_bounds__(256) void proj_qkv(
    const float* __restrict__ X,
    const float* __restrict__ Wq, const float* __restrict__ bq,
    const float* __restrict__ Wk, const float* __restrict__ bk,
    const float* __restrict__ Wv, const float* __restrict__ bv,
    float* __restrict__ Qf, float* __restrict__ Kf, u16* __restrict__ Vb)
{
    const int z = blockIdx.y;
    const float* __restrict__ W    = (z == 0) ? Wq : (z == 1) ? Wk : Wv;
    const float* __restrict__ bias = (z == 0) ? bq : (z == 1) ? bk : bv;

    const int m0   = blockIdx.x * 64;
    const int t    = threadIdx.x;
    const int w    = t >> 6;
    const int lane = t & 63;
    const int quad = lane >> 4;
    const int l16  = lane & 15;

    __shared__ __align__(16) u16 Xh[64 * 40],  Xl[64 * 40];
    __shared__ __align__(16) u16 Wh[256 * 40], Wl[256 * 40];

    f32x4 acc[16];
#pragma unroll
    for (int i = 0; i < 16; ++i) acc[i] = f32x4{0.f, 0.f, 0.f, 0.f};

    for (int kc = 0; kc < 8; ++kc) {
#pragma unroll
        for (int i = 0; i < 2; ++i) {          // X tile: 512 f4-chunks
            const int ch = i * 256 + t;
            const int row = ch >> 3, cg = ch & 7;
            const float4 v = *(const float4*)&X[(size_t)(m0 + row) * 256 + kc * 32 + cg * 4];
            f4_split(v, &Xh[row * 40 + cg * 4], &Xl[row * 40 + cg * 4]);
        }
#pragma unroll
        for (int i = 0; i < 8; ++i) {          // W tile: 2048 f4-chunks
            const int ch = i * 256 + t;
            const int row = ch >> 3, cg = ch & 7;
            const float4 v = *(const float4*)&W[(size_t)row * 256 + kc * 32 + cg * 4];
            f4_split(v, &Wh[row * 40 + cg * 4], &Wl[row * 40 + cg * 4]);
        }
        __syncthreads();

        const bf16x8 ah = *(const bf16x8*)&Xh[(w * 16 + l16) * 40 + quad * 8];
        const bf16x8 al = *(const bf16x8*)&Xl[(w * 16 + l16) * 40 + quad * 8];
#pragma unroll
        for (int nt = 0; nt < 16; ++nt) {
            const bf16x8 bh = *(const bf16x8*)&Wh[(nt * 16 + l16) * 40 + quad * 8];
            const bf16x8 bl = *(const bf16x8*)&Wl[(nt * 16 + l16) * 40 + quad * 8];
            acc[nt] = MFMA16x16x32(ah, bh, acc[nt], 0, 0, 0);
            acc[nt] = MFMA16x16x32(ah, bl, acc[nt], 0, 0, 0);
            acc[nt] = MFMA16x16x32(al, bh, acc[nt], 0, 0, 0);
        }
        __syncthreads();
    }

#pragma unroll
    for (int nt = 0; nt < 16; ++nt) {
        const int col = nt * 16 + l16;
        const float bb = bias[col];
#pragma unroll
        for (int r = 0; r < 4; ++r) {
            const size_t idx = (size_t)(m0 + w * 16 + quad * 4 + r) * 256 + col;
            const float y = acc[nt][r] + bb;
            if (z == 0)      Qf[idx] = y;
            else if (z == 1) Kf[idx] = y;
            else             Vb[idx] = f2bf(y);
        }
    }
}

// ---------------------------------------------------------------------------
// Kernel 2: per-batch transpose V[b][n][d] -> Vt[b][d][n]   (bf16)
// ---------------------------------------------------------------------------
__global__ __launch_bounds__(256) void transpose_v(
    const u16* __restrict__ V, u16* __restrict__ Vt)
{
    __shared__ u16 tile[32][33];
    const int b  = blockIdx.z;
    const int n0 = blockIdx.x * 32;
    const int d0 = blockIdx.y * 32;
    const int tx = threadIdx.x;   // 0..31
    const int ty = threadIdx.y;   // 0..7
#pragma unroll
    for (int i = 0; i < 4; ++i)
        tile[ty + 8 * i][tx] =
            V[(size_t)(b * 2048 + n0 + ty + 8 * i) * 256 + d0 + tx];
    __syncthreads();
#pragma unroll
    for (int i = 0; i < 4; ++i)
        Vt[(size_t)b * 524288 + (size_t)(d0 + ty + 8 * i) * 2048 + n0 + tx] =
            tile[tx][ty + 8 * i];
}

// ---------------------------------------------------------------------------
// Kernel 3: flash attention, split-bf16 QK^T (3-term), bf16 PV.
// Q,K fp32 in; loc fp32 out (written into d_out region).
// ---------------------------------------------------------------------------
__global__ __launch_bounds__(256) void attn(
    const float* __restrict__ Qf, const float* __restrict__ Kf,
    const u16* __restrict__ Vt, float* __restrict__ loc)
{
    const int b  = blockIdx.y;
    const int q0 = blockIdx.x * 64;
    const int t    = threadIdx.x;
    const int w    = t >> 6;
    const int lane = t & 63;
    const int quad = lane >> 4;
    const int l16  = lane & 15;

    __shared__ __align__(16) u16 Kh[32 * 264], Kl[32 * 264];  // 32 keys x 256 (+8)
    __shared__ __align__(16) u16 Vs[256 * 40];                // 256 dv x 32 keys (+8)
    __shared__ __align__(16) u16 Ps[4][16 * 40];              // per-wave P

    // Q fragments, split: A[m=l16][k=quad*8+j], k_total = kc*32 + quad*8 + j
    bf16x8 qh[8], ql[8];
    {
        const size_t qrow = (size_t)(b * 2048 + q0 + w * 16 + l16) * 256;
#pragma unroll
        for (int kc = 0; kc < 8; ++kc) {
            const float4 v0 = *(const float4*)&Qf[qrow + kc * 32 + quad * 8];
            const float4 v1 = *(const float4*)&Qf[qrow + kc * 32 + quad * 8 + 4];
            u16 h[8], l[8];
            f4_split(v0, h, l);
            f4_split(v1, h + 4, l + 4);
#pragma unroll
            for (int j = 0; j < 8; ++j) { qh[kc][j] = (short)h[j]; ql[kc][j] = (short)l[j]; }
        }
    }

    f32x4 O[16];
#pragma unroll
    for (int i = 0; i < 16; ++i) O[i] = f32x4{0.f, 0.f, 0.f, 0.f};
    float mrow[4], lrow[4];
#pragma unroll
    for (int r = 0; r < 4; ++r) { mrow[r] = -1e30f; lrow[r] = 0.f; }

    for (int kt0 = 0; kt0 < 2048; kt0 += 32) {
        // stage K tile fp32 -> split hi/lo: 32 rows x 64 f4 = 2048 chunks
#pragma unroll
        for (int i = 0; i < 8; ++i) {
            const int ch = i * 256 + t;
            const int row = ch >> 6, cg = ch & 63;
            const float4 v = *(const float4*)&Kf[(size_t)(b * 2048 + kt0 + row) * 256 + cg * 4];
            f4_split(v, &Kh[row * 264 + cg * 4], &Kl[row * 264 + cg * 4]);
        }
        // stage Vt tile (bf16): 1024 int4-chunks
#pragma unroll
        for (int i = 0; i < 4; ++i) {
            const int ch = i * 256 + t;
            const int row = ch >> 2, cg = ch & 3;
            *(int4*)&Vs[row * 40 + cg * 8] =
                *(const int4*)&Vt[(size_t)b * 524288 + (size_t)row * 2048 + kt0 + cg * 8];
        }
        __syncthreads();

        f32x4 S[2];
        S[0] = f32x4{0.f, 0.f, 0.f, 0.f};
        S[1] = f32x4{0.f, 0.f, 0.f, 0.f};
#pragma unroll
        for (int kc = 0; kc < 8; ++kc) {
#pragma unroll
            for (int kn = 0; kn < 2; ++kn) {
                const bf16x8 bh = *(const bf16x8*)&Kh[(kn * 16 + l16) * 264 + kc * 32 + quad * 8];
                const bf16x8 bl = *(const bf16x8*)&Kl[(kn * 16 + l16) * 264 + kc * 32 + quad * 8];
                S[kn] = MFMA16x16x32(qh[kc], bh, S[kn], 0, 0, 0);
                S[kn] = MFMA16x16x32(qh[kc], bl, S[kn], 0, 0, 0);
                S[kn] = MFMA16x16x32(ql[kc], bh, S[kn], 0, 0, 0);
            }
        }

        float P[2][4];
#pragma unroll
        for (int r = 0; r < 4; ++r) {
            float mt = fmaxf(S[0][r], S[1][r]);
            mt = fmaxf(mt, __shfl_xor(mt, 1));
            mt = fmaxf(mt, __shfl_xor(mt, 2));
            mt = fmaxf(mt, __shfl_xor(mt, 4));
            mt = fmaxf(mt, __shfl_xor(mt, 8));
            const float mnew  = fmaxf(mrow[r], mt);
            const float alpha = __expf(mrow[r] - mnew);
            const float p0 = __expf(S[0][r] - mnew);
            const float p1 = __expf(S[1][r] - mnew);
            float s = p0 + p1;
            s += __shfl_xor(s, 1);
            s += __shfl_xor(s, 2);
            s += __shfl_xor(s, 4);
            s += __shfl_xor(s, 8);
            lrow[r] = alpha * lrow[r] + s;
            mrow[r] = mnew;
            P[0][r] = p0; P[1][r] = p1;
#pragma unroll
            for (int dv = 0; dv < 16; ++dv) O[dv][r] *= alpha;
        }

        // P: C/D layout -> LDS -> A layout (u16 both ways + barrier)
#pragma unroll
        for (int kn = 0; kn < 2; ++kn)
#pragma unroll
            for (int r = 0; r < 4; ++r)
                Ps[w][(quad * 4 + r) * 40 + kn * 16 + l16] = f2bf(P[kn][r]);
        __syncthreads();

        bf16x8 af;
#pragma unroll
        for (int j = 0; j < 8; ++j)
            af[j] = (short)Ps[w][l16 * 40 + quad * 8 + j];

#pragma unroll
        for (int dv = 0; dv < 16; ++dv) {
            const bf16x8 bf = *(const bf16x8*)&Vs[(dv * 16 + l16) * 40 + quad * 8];
            O[dv] = MFMA16x16x32(af, bf, O[dv], 0, 0, 0);
        }
        __syncthreads();
    }

#pragma unroll
    for (int r = 0; r < 4; ++r) {
        const float rl = 1.0f / lrow[r];
        const size_t row = (size_t)(b * 2048 + q0 + w * 16 + quad * 4 + r) * 256;
#pragma unroll
        for (int dv = 0; dv < 16; ++dv)
            loc[row + dv * 16 + l16] = O[dv][r] * rl;
    }
}

// ---------------------------------------------------------------------------
// Kernel 4: out projection (split-bf16) + bias + LayerNorm + LeakyReLU.
// L aliases out (fp32): each block's global reads of its 64 rows all
// complete before its epilogue stores. NO __restrict__ on L/out.
// ---------------------------------------------------------------------------
__global__ __launch_bounds__(256) void outproj_ln(
    const float* L, const float* __restrict__ Wo,
    const float* __restrict__ bo, const float* __restrict__ gamma,
    const float* __restrict__ beta, float* out)
{
    const int m0   = blockIdx.x * 64;
    const int t    = threadIdx.x;
    const int w    = t >> 6;
    const int lane = t & 63;
    const int quad = lane >> 4;
    const int l16  = lane & 15;

    __shared__ __align__(16) u16 Lh[64 * 40],  Ll[64 * 40];
    __shared__ __align__(16) u16 Wh[256 * 40], Wl[256 * 40];

    f32x4 acc[16];
#pragma unroll
    for (int i = 0; i < 16; ++i) acc[i] = f32x4{0.f, 0.f, 0.f, 0.f};

    for (int kc = 0; kc < 8; ++kc) {
#pragma unroll
        for (int i = 0; i < 2; ++i) {
            const int ch = i * 256 + t;
            const int row = ch >> 3, cg = ch & 7;
            const float4 v = *(const float4*)&L[(size_t)(m0 + row) * 256 + kc * 32 + cg * 4];
            f4_split(v, &Lh[row * 40 + cg * 4], &Ll[row * 40 + cg * 4]);
        }
#pragma unroll
        for (int i = 0; i < 8; ++i) {
            const int ch = i * 256 + t;
            const int row = ch >> 3, cg = ch & 7;
            const float4 v = *(const float4*)&Wo[(size_t)row * 256 + kc * 32 + cg * 4];
            f4_split(v, &Wh[row * 40 + cg * 4], &Wl[row * 40 + cg * 4]);
        }
        __syncthreads();

        const bf16x8 ah = *(const bf16x8*)&Lh[(w * 16 + l16) * 40 + quad * 8];
        const bf16x8 al = *(const bf16x8*)&Ll[(w * 16 + l16) * 40 + quad * 8];
#pragma unroll
        for (int nt = 0; nt < 16; ++nt) {
            const bf16x8 bh = *(const bf16x8*)&Wh[(nt * 16 + l16) * 40 + quad * 8];
            const bf16x8 bl = *(const bf16x8*)&Wl[(nt * 16 + l16) * 40 + quad * 8];
            acc[nt] = MFMA16x16x32(ah, bh, acc[nt], 0, 0, 0);
            acc[nt] = MFMA16x16x32(ah, bl, acc[nt], 0, 0, 0);
            acc[nt] = MFMA16x16x32(al, bh, acc[nt], 0, 0, 0);
        }
        __syncthreads();
    }

    float g[16], bt[16], bb[16];
#pragma unroll
    for (int nt = 0; nt < 16; ++nt) {
        const int col = nt * 16 + l16;
        bb[nt] = bo[col];
        g[nt]  = gamma[col];
        bt[nt] = beta[col];
    }

#pragma unroll
    for (int r = 0; r < 4; ++r) {
        float h[16];
        float sh = 0.f, sh2 = 0.f;
#pragma unroll
        for (int nt = 0; nt < 16; ++nt) {
            h[nt] = acc[nt][r] + bb[nt];
            sh  += h[nt];
            sh2 += h[nt] * h[nt];
        }
        sh  += __shfl_xor(sh, 1);  sh  += __shfl_xor(sh, 2);
        sh  += __shfl_xor(sh, 4);  sh  += __shfl_xor(sh, 8);
        sh2 += __shfl_xor(sh2, 1); sh2 += __shfl_xor(sh2, 2);
        sh2 += __shfl_xor(sh2, 4); sh2 += __shfl_xor(sh2, 8);
        const float mu  = sh * (1.f / 256.f);
        const float var = fmaxf(sh2 * (1.f / 256.f) - mu * mu, 0.f);
        const float rs  = rsqrtf(var + 1e-5f);
        const size_t row = (size_t)(m0 + w * 16 + quad * 4 + r) * 256;
#pragma unroll
        for (int nt = 0; nt < 16; ++nt) {
            const float hn = (h[nt] - mu) * rs * g[nt] + bt[nt];
            const float y  = (hn >= 0.f) ? hn : 0.01f * hn;
            out[row + nt * 16 + l16] = y;
        }
    }
}

// ---------------------------------------------------------------------------
extern "C" void kernel_launch(void* const* d_in, const int* in_sizes, int n_in,
                              void* d_out, int out_size, void* d_ws, size_t ws_size,
                              hipStream_t stream)
{
    const float* x  = (const float*)d_in[0];
    const float* Wq = (const float*)d_in[1];
    const float* bq = (const float*)d_in[2];
    const float* Wk = (const float*)d_in[3];
    const float* bk = (const float*)d_in[4];
    const float* Wv = (const float*)d_in[5];
    const float* bv = (const float*)d_in[6];
    const float* Wo = (const float*)d_in[7];
    const float* bo = (const float*)d_in[8];
    const float* gm = (const float*)d_in[9];
    const float* bt = (const float*)d_in[10];
    float* out = (float*)d_out;

    // ws: Qf32 (16.78MB), Kf32 (16.78MB), V bf16 (8.39MB), Vt bf16 (8.39MB)
    //     = 48 MB total.  loc (fp32) lives in d_out.
    float* Qf = (float*)d_ws;
    float* Kf = Qf + 4194304;
    u16*   V  = (u16*)(Kf + 4194304);
    u16*   Vt = V + 4194304;
    float* L  = out;

    proj_qkv   <<<dim3(256, 3),   256,        0, stream>>>(x, Wq, bq, Wk, bk, Wv, bv, Qf, Kf, V);
    transpose_v<<<dim3(64, 8, 8), dim3(32,8), 0, stream>>>(V, Vt);
    attn       <<<dim3(32, 8),    256,        0, stream>>>(Qf, Kf, Vt, L);
    outproj_ln <<<256,            256,        0, stream>>>(L, Wo, bo, gm, bt, out);
}

// Round 6
// 220.063 us; speedup vs baseline: 1.6503x; 1.6503x over previous
//
#include <hip/hip_runtime.h>

typedef unsigned short u16;
typedef __attribute__((ext_vector_type(8))) _Float16 f16x8;
typedef __attribute__((ext_vector_type(4))) float f32x4;

#define MFMA_F16 __builtin_amdgcn_mfma_f32_16x16x32_f16

static __device__ __forceinline__ u16 f2h(float f) {
    return __builtin_bit_cast(u16, (_Float16)f);
}
static __device__ __forceinline__ ushort4 f4_to_h4(const float4 v) {
    ushort4 r;
    r.x = f2h(v.x); r.y = f2h(v.y); r.z = f2h(v.z); r.w = f2h(v.w);
    return r;
}

// ---------------------------------------------------------------------------
// Kernel 0: prep — convert x (4.19M) and Wq/Wk/Wv/Wo (4x65536) fp32 -> fp16.
// ---------------------------------------------------------------------------
__global__ __launch_bounds__(256) void prep(
    const float* __restrict__ x,
    const float* __restrict__ wq, const float* __restrict__ wk,
    const float* __restrict__ wv, const float* __restrict__ wo,
    u16* __restrict__ xh, u16* __restrict__ w4)
{
    const int tid = blockIdx.x * 256 + threadIdx.x;
    // x: 1048576 float4 chunks over 524288 threads -> 2 each
    for (int i = tid; i < 1048576; i += 2048 * 256)
        ((ushort4*)xh)[i] = f4_to_h4(((const float4*)x)[i]);
    // W: 65536 float4 chunks over first 64 blocks (16384 threads) -> 4 each
    if (blockIdx.x < 64) {
        for (int i = tid; i < 65536; i += 16384) {
            const float* src = (i < 16384) ? wq : (i < 32768) ? wk
                             : (i < 49152) ? wv : wo;
            ((ushort4*)w4)[i] = f4_to_h4(((const float4*)src)[i & 16383]);
        }
    }
}

// ---------------------------------------------------------------------------
// Kernel 1: Q/K/V projection, fp16.  Y = X @ W^T + b.
// grid (256 m-tiles, 3 z). Inputs pre-converted fp16.
// ---------------------------------------------------------------------------
__global__ __launch_bounds__(256) void proj_qkv(
    const u16* __restrict__ xh, const u16* __restrict__ w4,
    const float* __restrict__ bq, const float* __restrict__ bk,
    const float* __restrict__ bv,
    u16* __restrict__ Qh, u16* __restrict__ Kh, u16* __restrict__ V)
{
    const int z = blockIdx.y;
    const u16* __restrict__ W     = w4 + z * 65536;
    const float* __restrict__ bias = (z == 0) ? bq : (z == 1) ? bk : bv;
    u16* __restrict__ Y            = (z == 0) ? Qh : (z == 1) ? Kh : V;

    const int m0   = blockIdx.x * 64;
    const int t    = threadIdx.x;
    const int w    = t >> 6;
    const int lane = t & 63;
    const int quad = lane >> 4;
    const int l16  = lane & 15;

    __shared__ __align__(16) u16 Xs[64 * 40];    // 64 x 32 (+8 pad)
    __shared__ __align__(16) u16 Ws[256 * 40];   // 256 x 32 (+8 pad)

    f32x4 acc[16];
#pragma unroll
    for (int i = 0; i < 16; ++i) acc[i] = f32x4{0.f, 0.f, 0.f, 0.f};

    for (int kc = 0; kc < 8; ++kc) {
        {   // X tile: 256 int4-chunks, 1/thread
            const int row = t >> 2, cg = t & 3;
            *(int4*)&Xs[row * 40 + cg * 8] =
                *(const int4*)&xh[(size_t)(m0 + row) * 256 + kc * 32 + cg * 8];
        }
#pragma unroll
        for (int i = 0; i < 4; ++i) {   // W tile: 1024 chunks, 4/thread
            const int ch = i * 256 + t;
            const int row = ch >> 2, cg = ch & 3;
            *(int4*)&Ws[row * 40 + cg * 8] =
                *(const int4*)&W[(size_t)row * 256 + kc * 32 + cg * 8];
        }
        __syncthreads();

        const f16x8 af = *(const f16x8*)&Xs[(w * 16 + l16) * 40 + quad * 8];
#pragma unroll
        for (int nt = 0; nt < 16; ++nt) {
            const f16x8 bf = *(const f16x8*)&Ws[(nt * 16 + l16) * 40 + quad * 8];
            acc[nt] = MFMA_F16(af, bf, acc[nt], 0, 0, 0);
        }
        __syncthreads();
    }

#pragma unroll
    for (int nt = 0; nt < 16; ++nt) {
        const int col = nt * 16 + l16;
        const float bb = bias[col];
#pragma unroll
        for (int r = 0; r < 4; ++r) {
            const int row = m0 + w * 16 + quad * 4 + r;
            Y[(size_t)row * 256 + col] = f2h(acc[nt][r] + bb);
        }
    }
}

// ---------------------------------------------------------------------------
// Kernel 2: per-batch transpose V[b][n][d] -> Vt[b][d][n]   (fp16)
// ---------------------------------------------------------------------------
__global__ __launch_bounds__(256) void transpose_v(
    const u16* __restrict__ V, u16* __restrict__ Vt)
{
    __shared__ u16 tile[32][33];
    const int b  = blockIdx.z;
    const int n0 = blockIdx.x * 32;
    const int d0 = blockIdx.y * 32;
    const int tx = threadIdx.x;
    const int ty = threadIdx.y;
#pragma unroll
    for (int i = 0; i < 4; ++i)
        tile[ty + 8 * i][tx] =
            V[(size_t)(b * 2048 + n0 + ty + 8 * i) * 256 + d0 + tx];
    __syncthreads();
#pragma unroll
    for (int i = 0; i < 4; ++i)
        Vt[(size_t)b * 524288 + (size_t)(d0 + ty + 8 * i) * 2048 + n0 + tx] =
            tile[tx][ty + 8 * i];
}

// ---------------------------------------------------------------------------
// Kernel 3: flash attention, fp16, split-K x2.
// grid (32 q-tiles, 8 batches, 2 halves). Each block: 64 q x 1024 keys.
// Writes normalized partial O (fp16) + l,m (fp32) for exact combine.
// ---------------------------------------------------------------------------
__global__ __launch_bounds__(256) void attn(
    const u16* __restrict__ Qh, const u16* __restrict__ Kg,
    const u16* __restrict__ Vt, u16* __restrict__ Op, float* __restrict__ lmp)
{
    const int b  = blockIdx.y;
    const int q0 = blockIdx.x * 64;
    const int z  = blockIdx.z;
    const int kbase = z * 1024;
    const int t    = threadIdx.x;
    const int w    = t >> 6;
    const int lane = t & 63;
    const int quad = lane >> 4;
    const int l16  = lane & 15;

    __shared__ __align__(16) u16 Ks[32 * 264];     // 32 keys x 256 (+8 pad)
    __shared__ __align__(16) u16 Vs[256 * 40];     // 256 dv x 32 keys (+8)
    __shared__ __align__(16) u16 Ps[4][16 * 40];   // per-wave P

    f16x8 qf[8];
    {
        const size_t qrow = (size_t)(b * 2048 + q0 + w * 16 + l16) * 256;
#pragma unroll
        for (int kc = 0; kc < 8; ++kc)
            qf[kc] = *(const f16x8*)&Qh[qrow + kc * 32 + quad * 8];
    }

    f32x4 O[16];
#pragma unroll
    for (int i = 0; i < 16; ++i) O[i] = f32x4{0.f, 0.f, 0.f, 0.f};
    float mrow[4], lrow[4];
#pragma unroll
    for (int r = 0; r < 4; ++r) { mrow[r] = -1e30f; lrow[r] = 0.f; }

    for (int kt0 = 0; kt0 < 1024; kt0 += 32) {
        // K tile: 1024 int4-chunks, 4/thread (fp16, no conversion)
#pragma unroll
        for (int i = 0; i < 4; ++i) {
            const int ch = i * 256 + t;
            const int row = ch >> 5, cg = ch & 31;
            *(int4*)&Ks[row * 264 + cg * 8] =
                *(const int4*)&Kg[(size_t)(b * 2048 + kbase + kt0 + row) * 256 + cg * 8];
        }
        // Vt tile: 1024 int4-chunks, 4/thread
#pragma unroll
        for (int i = 0; i < 4; ++i) {
            const int ch = i * 256 + t;
            const int row = ch >> 2, cg = ch & 3;
            *(int4*)&Vs[row * 40 + cg * 8] =
                *(const int4*)&Vt[(size_t)b * 524288 + (size_t)row * 2048 + kbase + kt0 + cg * 8];
        }
        __syncthreads();

        f32x4 S[2];
        S[0] = f32x4{0.f, 0.f, 0.f, 0.f};
        S[1] = f32x4{0.f, 0.f, 0.f, 0.f};
#pragma unroll
        for (int kc = 0; kc < 8; ++kc) {
#pragma unroll
            for (int kn = 0; kn < 2; ++kn) {
                const f16x8 bf = *(const f16x8*)&Ks[(kn * 16 + l16) * 264 + kc * 32 + quad * 8];
                S[kn] = MFMA_F16(qf[kc], bf, S[kn], 0, 0, 0);
            }
        }

        float P[2][4], a4[4];
#pragma unroll
        for (int r = 0; r < 4; ++r) {
            float mt = fmaxf(S[0][r], S[1][r]);
            mt = fmaxf(mt, __shfl_xor(mt, 1));
            mt = fmaxf(mt, __shfl_xor(mt, 2));
            mt = fmaxf(mt, __shfl_xor(mt, 4));
            mt = fmaxf(mt, __shfl_xor(mt, 8));
            const float mnew = fmaxf(mrow[r], mt);
            a4[r] = __expf(mrow[r] - mnew);
            const float p0 = __expf(S[0][r] - mnew);
            const float p1 = __expf(S[1][r] - mnew);
            float s = p0 + p1;
            s += __shfl_xor(s, 1);
            s += __shfl_xor(s, 2);
            s += __shfl_xor(s, 4);
            s += __shfl_xor(s, 8);
            lrow[r] = a4[r] * lrow[r] + s;
            mrow[r] = mnew;
            P[0][r] = p0; P[1][r] = p1;
        }
        // rescale O only when a max actually moved (quad-uniform branch)
        if (a4[0] < 1.f || a4[1] < 1.f || a4[2] < 1.f || a4[3] < 1.f) {
#pragma unroll
            for (int dv = 0; dv < 16; ++dv)
#pragma unroll
                for (int r = 0; r < 4; ++r) O[dv][r] *= a4[r];
        }

        // P: C/D layout -> per-wave LDS -> A layout. Wave-local fence suffices
        // (only this wave reads Ps[w]); lgkmcnt(0) drains the ds_writes.
#pragma unroll
        for (int kn = 0; kn < 2; ++kn)
#pragma unroll
            for (int r = 0; r < 4; ++r)
                Ps[w][(quad * 4 + r) * 40 + kn * 16 + l16] = f2h(P[kn][r]);
        asm volatile("s_waitcnt lgkmcnt(0)" ::: "memory");

        const f16x8 af = *(const f16x8*)&Ps[w][l16 * 40 + quad * 8];
#pragma unroll
        for (int dv = 0; dv < 16; ++dv) {
            const f16x8 bf = *(const f16x8*)&Vs[(dv * 16 + l16) * 40 + quad * 8];
            O[dv] = MFMA_F16(af, bf, O[dv], 0, 0, 0);
        }
        __syncthreads();
    }

    // write normalized partial: Op[z] = O/l (fp16), lmp: l then m (fp32)
    u16* __restrict__ Oz = Op + (size_t)z * 4194304;
#pragma unroll
    for (int r = 0; r < 4; ++r) {
        const float rl = 1.0f / lrow[r];
        const int grow = b * 2048 + q0 + w * 16 + quad * 4 + r;
        const size_t rowoff = (size_t)grow * 256;
#pragma unroll
        for (int dv = 0; dv < 16; ++dv)
            Oz[rowoff + dv * 16 + l16] = f2h(O[dv][r] * rl);
        if (l16 == 0) {
            lmp[z * 16384 + grow]         = lrow[r];
            lmp[32768 + z * 16384 + grow] = mrow[r];
        }
    }
}

// ---------------------------------------------------------------------------
// Kernel 4: combine partials + out projection + bias + LayerNorm + LeakyReLU.
// Combine: O = w0*O0 + w1*O1, w_h = l_h*exp(m_h - mmax) (normalized).
// ---------------------------------------------------------------------------
__global__ __launch_bounds__(256) void outproj_ln(
    const u16* __restrict__ Op, const float* __restrict__ lmp,
    const u16* __restrict__ Woh, const float* __restrict__ bo,
    const float* __restrict__ gamma, const float* __restrict__ beta,
    float* __restrict__ out)
{
    const int m0   = blockIdx.x * 64;
    const int t    = threadIdx.x;
    const int w    = t >> 6;
    const int lane = t & 63;
    const int quad = lane >> 4;
    const int l16  = lane & 15;

    __shared__ __align__(16) u16 Ls[64 * 40];
    __shared__ __align__(16) u16 Ws[256 * 40];
    __shared__ _Float16 w0s[64], w1s[64];

    if (t < 64) {
        const float l0 = lmp[m0 + t],         l1 = lmp[16384 + m0 + t];
        const float mm0 = lmp[32768 + m0 + t], mm1 = lmp[49152 + m0 + t];
        const float mm = fmaxf(mm0, mm1);
        const float u0 = l0 * __expf(mm0 - mm);
        const float u1 = l1 * __expf(mm1 - mm);
        const float inv = 1.0f / (u0 + u1);
        w0s[t] = (_Float16)(u0 * inv);
        w1s[t] = (_Float16)(u1 * inv);
    }
    __syncthreads();

    f32x4 acc[16];
#pragma unroll
    for (int i = 0; i < 16; ++i) acc[i] = f32x4{0.f, 0.f, 0.f, 0.f};

    for (int kc = 0; kc < 8; ++kc) {
        {   // combined L tile: 256 chunks, 1/thread
            const int row = t >> 2, cg = t & 3;
            const size_t off = (size_t)(m0 + row) * 256 + kc * 32 + cg * 8;
            const f16x8 o0 = __builtin_bit_cast(f16x8, *(const int4*)&Op[off]);
            const f16x8 o1 = __builtin_bit_cast(f16x8, *(const int4*)&Op[4194304 + off]);
            const _Float16 w0 = w0s[row], w1 = w1s[row];
            f16x8 lw;
#pragma unroll
            for (int j = 0; j < 8; ++j) lw[j] = o0[j] * w0 + o1[j] * w1;
            *(int4*)&Ls[row * 40 + cg * 8] = __builtin_bit_cast(int4, lw);
        }
#pragma unroll
        for (int i = 0; i < 4; ++i) {   // Wo tile: 1024 chunks, 4/thread
            const int ch = i * 256 + t;
            const int row = ch >> 2, cg = ch & 3;
            *(int4*)&Ws[row * 40 + cg * 8] =
                *(const int4*)&Woh[(size_t)row * 256 + kc * 32 + cg * 8];
        }
        __syncthreads();

        const f16x8 af = *(const f16x8*)&Ls[(w * 16 + l16) * 40 + quad * 8];
#pragma unroll
        for (int nt = 0; nt < 16; ++nt) {
            const f16x8 bf = *(const f16x8*)&Ws[(nt * 16 + l16) * 40 + quad * 8];
            acc[nt] = MFMA_F16(af, bf, acc[nt], 0, 0, 0);
        }
        __syncthreads();
    }

    float g[16], bt[16], bb[16];
#pragma unroll
    for (int nt = 0; nt < 16; ++nt) {
        const int col = nt * 16 + l16;
        bb[nt] = bo[col]; g[nt] = gamma[col]; bt[nt] = beta[col];
    }

#pragma unroll
    for (int r = 0; r < 4; ++r) {
        float h[16];
        float sh = 0.f, sh2 = 0.f;
#pragma unroll
        for (int nt = 0; nt < 16; ++nt) {
            h[nt] = acc[nt][r] + bb[nt];
            sh  += h[nt];
            sh2 += h[nt] * h[nt];
        }
        sh  += __shfl_xor(sh, 1);  sh  += __shfl_xor(sh, 2);
        sh  += __shfl_xor(sh, 4);  sh  += __shfl_xor(sh, 8);
        sh2 += __shfl_xor(sh2, 1); sh2 += __shfl_xor(sh2, 2);
        sh2 += __shfl_xor(sh2, 4); sh2 += __shfl_xor(sh2, 8);
        const float mu  = sh * (1.f / 256.f);
        const float var = fmaxf(sh2 * (1.f / 256.f) - mu * mu, 0.f);
        const float rs  = rsqrtf(var + 1e-5f);
        const size_t row = (size_t)(m0 + w * 16 + quad * 4 + r) * 256;
#pragma unroll
        for (int nt = 0; nt < 16; ++nt) {
            const float hn = (h[nt] - mu) * rs * g[nt] + bt[nt];
            out[row + nt * 16 + l16] = (hn >= 0.f) ? hn : 0.01f * hn;
        }
    }
}

// ---------------------------------------------------------------------------
extern "C" void kernel_launch(void* const* d_in, const int* in_sizes, int n_in,
                              void* d_out, int out_size, void* d_ws, size_t ws_size,
                              hipStream_t stream)
{
    const float* x  = (const float*)d_in[0];
    const float* Wq = (const float*)d_in[1];
    const float* bq = (const float*)d_in[2];
    const float* Wk = (const float*)d_in[3];
    const float* bk = (const float*)d_in[4];
    const float* Wv = (const float*)d_in[5];
    const float* bv = (const float*)d_in[6];
    const float* Wo = (const float*)d_in[7];
    const float* bo = (const float*)d_in[8];
    const float* gm = (const float*)d_in[9];
    const float* bt = (const float*)d_in[10];
    float* out = (float*)d_out;

    // ws layout (u16 units). Op overlays dead V+xh regions:
    //   [W4 262144][Qh 4.19M][Kh 4.19M][Vt 4.19M][V 4.19M][xh 4.19M][lmp]
    //   Op0 = V region, Op1 = xh region (contiguous).  Total ~42.7 MB.
    u16* W4 = (u16*)d_ws;
    u16* Qh = W4 + 262144;
    u16* Kh = Qh + 4194304;
    u16* Vt = Kh + 4194304;
    u16* V  = Vt + 4194304;
    u16* xh = V  + 4194304;
    u16* Op = V;                       // 2 x 4194304 (overlays V, xh)
    float* lmp = (float*)(xh + 4194304);  // l[2][16384], m[2][16384]
    u16* Woh = W4 + 196608;

    prep       <<<2048,           256,        0, stream>>>(x, Wq, Wk, Wv, Wo, xh, W4);
    proj_qkv   <<<dim3(256, 3),   256,        0, stream>>>(xh, W4, bq, bk, bv, Qh, Kh, V);
    transpose_v<<<dim3(64, 8, 8), dim3(32,8), 0, stream>>>(V, Vt);
    attn       <<<dim3(32, 8, 2), 256,        0, stream>>>(Qh, Kh, Vt, Op, lmp);
    outproj_ln <<<256,            256,        0, stream>>>(Op, lmp, Woh, bo, gm, bt, out);
}